// Round 1
// baseline (573.149 us; speedup 1.0000x reference)
//
#include <hip/hip_runtime.h>
#include <hip/hip_bf16.h>

typedef __bf16 bf16_t;
typedef __bf16 bf16x4_t __attribute__((ext_vector_type(4)));
typedef __bf16 bf16x8_t __attribute__((ext_vector_type(8)));
typedef float f32x4_t __attribute__((ext_vector_type(4)));
typedef float f32x16_t __attribute__((ext_vector_type(16)));

typedef __attribute__((address_space(1))) void gvoid_t;
typedef __attribute__((address_space(3))) void svoid_t;

__device__ __forceinline__ void gload_lds16(const void* g, void* s) {
    // async global->LDS, 16B per lane; LDS dest = wave-uniform base + lane*16
    __builtin_amdgcn_global_load_lds((gvoid_t*)g, (svoid_t*)s, 16, 0, 0);
}

// Raw barrier WITHOUT the implicit vmcnt(0) drain __syncthreads() emits.
// The flanking empty asm is a compiler-level memory fence so no memory op
// (gload_lds / ds_read) is moved across the barrier.
__device__ __forceinline__ void wg_barrier() {
    asm volatile("" ::: "memory");
    __builtin_amdgcn_s_barrier();
    asm volatile("" ::: "memory");
}

// ---------------------------------------------------------------------------
// GEMM: C[M,N] = scale * (A[M,K] @ Bt[N,K]^T) + bias
//
// R4 (this round): 256x256 tile, 512 threads (8 waves, 2Mx4N), BK=32, with a
// 4-deep LDS ring and COUNTED vmcnt (T3+T4): loads stay in flight across
// barriers (steady state vmcnt(12) = 3 K-tiles outstanding), raw s_barrier
// (no vmcnt(0) drain), s_setprio around the MFMA cluster (T5).
//
// Pipeline invariants (hazard-proof):
//  - iteration j computes ring[j&3]; stages tile j+3 into ring[(j+3)&3]
//    = ring[(j-1)&3], whose readers all finished before the previous
//    end-barrier (explicit lgkmcnt(0) precedes it).
//  - vmcnt retires in order, so outstanding<=12 (= tiles j+1..j+3) proves
//    tile j has fully landed. Tail: vmcnt(8)/(4)/(0).
//
// LDS 16B-granule XOR swizzle kept from R1 (verified): physical chunk =
// logical ^ ((row>>1)&3), applied to the GLOBAL address on staging (the DMA
// forces linear LDS dest) and to the LDS offset on the read side.
// Fragments/epilogue reuse the verified 32x32x16 mappings.
// ---------------------------------------------------------------------------
template <typename CT, bool BIAS, bool STORE_T = false>
__global__ __launch_bounds__(512, 2)
void gemm_bt(const bf16_t* __restrict__ A, const bf16_t* __restrict__ Bt,
             CT* __restrict__ C, const float* __restrict__ bias,
             int M, int N, int K, float scale,
             size_t sA, size_t sB, size_t sC, int tshift)
{
    __shared__ bf16_t As[4 * 256 * 32];   // 64 KiB: 4-deep ring of 256x32
    __shared__ bf16_t Bs[4 * 256 * 32];   // 64 KiB

    // ---- tile swizzle (XCD remap + bands of 8 by-rows) --------------------
    const int nx = gridDim.x, ny = gridDim.y;
    const int nblk = nx * ny * (int)gridDim.z;
    int lin = blockIdx.x + nx * (blockIdx.y + ny * blockIdx.z);
    int tile = lin;
    if ((nblk & 7) == 0)
        tile = (lin & 7) * (nblk >> 3) + (lin >> 3);
    const int per_z = nx * ny;
    const int bz = tile / per_z;
    int t = tile - bz * per_z;
    const int SB = 8;
    const int band = t / (nx * SB);
    const int r = t - band * (nx * SB);
    const int h = min(SB, ny - band * SB);
    const int bx = r / h;
    const int by = band * SB + (r - bx * h);
    // -----------------------------------------------------------------------

    A  += (size_t)bz * sA;
    Bt += (size_t)bz * sB;
    C  += (size_t)bz * sC;

    const int tid  = threadIdx.x;          // 0..511
    const int wave = tid >> 6;
    const int lane = tid & 63;
    const int m0 = by * 256;
    const int n0 = bx * 256;

    // staging: thread t covers row rr = t>>2 (+128 for second half-op),
    // chunk t&3; the chunk holds logical k-granule (t&3)^((rr>>1)&3).
    // (row+128 has identical bits 1-2, so the same cc applies to both ops.)
    const int rr = tid >> 2;
    const int cc = ((tid & 3) ^ ((rr >> 1) & 3)) * 8;
    const bf16_t* aw0 = A  + (size_t)(m0 + rr) * K + cc;
    const bf16_t* aw1 = aw0 + (size_t)128 * K;
    const bf16_t* bw0 = Bt + (size_t)(n0 + rr) * K + cc;
    const bf16_t* bw1 = bw0 + (size_t)128 * K;
    const int soff0 = wave * 512;          // elements; +lane*16B implied
    const int soff1 = 4096 + wave * 512;

    // 32x32x16 fragment addressing (verified):
    //   A/B operand: m(or n) = lane&31, k = (lane>>5)*8 + j
    const int wm = wave >> 2;              // 0..1  -> rows wm*128..+128
    const int wn = wave & 3;               // 0..3  -> cols wn*64..+64
    const int lr = lane & 31;
    const int kh = lane >> 5;
    const int swz = (lr >> 1) & 3;         // row bits 1-2 (mi*32/wm*128 don't touch)

    f32x16_t acc[4][2];
#pragma unroll
    for (int i = 0; i < 4; ++i)
#pragma unroll
        for (int j = 0; j < 2; ++j)
            acc[i][j] = (f32x16_t)(0.f);

    const int NT = K >> 5;                 // K-tiles of 32

    auto stage = [&](int buf) {
        bf16_t* a = As + buf * 8192;
        bf16_t* b = Bs + buf * 8192;
        gload_lds16(aw0, a + soff0);
        gload_lds16(aw1, a + soff1);
        gload_lds16(bw0, b + soff0);
        gload_lds16(bw1, b + soff1);
        aw0 += 32; aw1 += 32; bw0 += 32; bw1 += 32;
    };

    // prologue: 3 tiles in flight
    stage(0);
    if (NT > 1) stage(1);
    if (NT > 2) stage(2);

    for (int j = 0; j < NT; ++j) {
        const int buf = j & 3;
        if (j + 3 < NT) {
            stage((j + 3) & 3);
            asm volatile("s_waitcnt vmcnt(12)" ::: "memory");  // tile j landed
        } else if (j + 2 < NT) {
            asm volatile("s_waitcnt vmcnt(8)" ::: "memory");
        } else if (j + 1 < NT) {
            asm volatile("s_waitcnt vmcnt(4)" ::: "memory");
        } else {
            asm volatile("s_waitcnt vmcnt(0)" ::: "memory");
        }
        wg_barrier();                      // everyone's tile-j data visible

        const bf16_t* ab = As + buf * 8192;
        const bf16_t* bb = Bs + buf * 8192;
        bf16x8_t af[4][2], bfr[2][2];
#pragma unroll
        for (int mi = 0; mi < 4; ++mi)
#pragma unroll
            for (int kk = 0; kk < 2; ++kk)
                af[mi][kk] = *(const bf16x8_t*)
                    &ab[(wm * 128 + mi * 32 + lr) * 32 + ((2 * kk + kh) ^ swz) * 8];
#pragma unroll
        for (int nj = 0; nj < 2; ++nj)
#pragma unroll
            for (int kk = 0; kk < 2; ++kk)
                bfr[nj][kk] = *(const bf16x8_t*)
                    &bb[(wn * 64 + nj * 32 + lr) * 32 + ((2 * kk + kh) ^ swz) * 8];

        __builtin_amdgcn_s_setprio(1);
#pragma unroll
        for (int kk = 0; kk < 2; ++kk)
#pragma unroll
            for (int mi = 0; mi < 4; ++mi)
#pragma unroll
                for (int nj = 0; nj < 2; ++nj)
                    acc[mi][nj] = __builtin_amdgcn_mfma_f32_32x32x16_bf16(
                        af[mi][kk], bfr[nj][kk], acc[mi][nj], 0, 0, 0);
        __builtin_amdgcn_s_setprio(0);

        // write-after-read protocol: all my ds_reads retired before I let
        // anyone start overwriting this ring slot (next iteration's stage).
        asm volatile("s_waitcnt lgkmcnt(0)" ::: "memory");
        wg_barrier();
    }

    // 32x32 C/D layout: col = lane&31, row = (reg&3)+8*(reg>>2)+4*(lane>>5)
#pragma unroll
    for (int nj = 0; nj < 2; ++nj) {
        const int col = n0 + wn * 64 + nj * 32 + lr;
        const float bv = BIAS ? bias[col] : 0.0f;
#pragma unroll
        for (int mi = 0; mi < 4; ++mi) {
            f32x16_t v = acc[mi][nj];
#pragma unroll
            for (int g = 0; g < 4; ++g) {
                const int row = m0 + wm * 128 + mi * 32 + 8 * g + 4 * kh;
                if constexpr (STORE_T) {
                    const int b = row >> tshift;
                    const int l = row & ((1 << tshift) - 1);
                    bf16x4_t o;
#pragma unroll
                    for (int rr2 = 0; rr2 < 4; ++rr2)
                        o[rr2] = (bf16_t)(v[g * 4 + rr2] * scale + bv);
                    *(bf16x4_t*)((bf16_t*)C + ((size_t)b * N << tshift) +
                                 ((size_t)col << tshift) + l) = o;
                } else {
#pragma unroll
                    for (int rr2 = 0; rr2 < 4; ++rr2) {
                        float val = v[g * 4 + rr2] * scale + bv;
                        C[(size_t)(row + rr2) * N + col] = (CT)val;
                    }
                }
            }
        }
    }
}

// ---------------------------------------------------------------------------
// LayerNorm: one wave per row, D = NV*256 (NV float4 per lane). fp32 in,
// bf16 out.
// ---------------------------------------------------------------------------
template <int NV>
__global__ __launch_bounds__(256, 4)
void layernorm_k(const float* __restrict__ x, const float* __restrict__ g,
                 const float* __restrict__ b, bf16_t* __restrict__ y)
{
    const int D = NV * 256;
    const int wave = threadIdx.x >> 6, lane = threadIdx.x & 63;
    const size_t row = (size_t)blockIdx.x * 4 + wave;
    const float4* xr = (const float4*)(x + row * D);

    float4 v[NV];
    float s = 0.f, sq = 0.f;
#pragma unroll
    for (int i = 0; i < NV; ++i) {
        v[i] = xr[lane + 64 * i];
        s  += v[i].x + v[i].y + v[i].z + v[i].w;
        sq += v[i].x * v[i].x + v[i].y * v[i].y + v[i].z * v[i].z + v[i].w * v[i].w;
    }
#pragma unroll
    for (int m = 32; m; m >>= 1) {
        s  += __shfl_xor(s, m, 64);
        sq += __shfl_xor(sq, m, 64);
    }
    const float mean = s / D;
    const float rstd = rsqrtf(fmaxf(sq / D - mean * mean, 0.f) + 1e-5f);

#pragma unroll
    for (int i = 0; i < NV; ++i) {
        const int c4 = lane + 64 * i;
        float4 gg = ((const float4*)g)[c4];
        float4 bb = ((const float4*)b)[c4];
        bf16x4_t o;
        o[0] = (bf16_t)((v[i].x - mean) * rstd * gg.x + bb.x);
        o[1] = (bf16_t)((v[i].y - mean) * rstd * gg.y + bb.y);
        o[2] = (bf16_t)((v[i].z - mean) * rstd * gg.z + bb.z);
        o[3] = (bf16_t)((v[i].w - mean) * rstd * gg.w + bb.w);
        *(bf16x4_t*)(y + row * D + (size_t)c4 * 4) = o;
    }
}

// ---------------------------------------------------------------------------
// In-place row softmax over 2048 bf16 entries; one wave per row.
// ---------------------------------------------------------------------------
__global__ __launch_bounds__(256, 4)
void softmax_rows(bf16_t* __restrict__ a)
{
    const int wave = threadIdx.x >> 6, lane = threadIdx.x & 63;
    const size_t row = (size_t)blockIdx.x * 4 + wave;
    bf16_t* r = a + row * 2048;

    float v[32];
    float mx = -3.0e38f;
#pragma unroll
    for (int i = 0; i < 4; ++i) {
        bf16x8_t t = *(const bf16x8_t*)(r + (size_t)(lane + 64 * i) * 8);
#pragma unroll
        for (int j = 0; j < 8; ++j) {
            v[i * 8 + j] = (float)t[j];
            mx = fmaxf(mx, v[i * 8 + j]);
        }
    }
#pragma unroll
    for (int m = 32; m; m >>= 1) mx = fmaxf(mx, __shfl_xor(mx, m, 64));
    float s = 0.f;
#pragma unroll
    for (int i = 0; i < 32; ++i) { v[i] = __expf(v[i] - mx); s += v[i]; }
#pragma unroll
    for (int m = 32; m; m >>= 1) s += __shfl_xor(s, m, 64);
    const float rs = 1.0f / s;
#pragma unroll
    for (int i = 0; i < 4; ++i) {
        bf16x8_t t;
#pragma unroll
        for (int j = 0; j < 8; ++j) t[j] = (bf16_t)(v[i * 8 + j] * rs);
        *(bf16x8_t*)(r + (size_t)(lane + 64 * i) * 8) = t;
    }
}

// ---------------------------------------------------------------------------
// fp32 weight [K][N] -> bf16 transposed [N][K]. 32x32 LDS tile.
// ---------------------------------------------------------------------------
__global__ __launch_bounds__(256, 4)
void wconvT(const float* __restrict__ w, bf16_t* __restrict__ wt, int K, int N)
{
    __shared__ float s[32][33];
    const int tx = threadIdx.x, ty = threadIdx.y;   // block (32,8)
    const int n0 = blockIdx.x * 32, k0 = blockIdx.y * 32;
#pragma unroll
    for (int r = 0; r < 4; ++r)
        s[ty + r * 8][tx] = w[(size_t)(k0 + ty + r * 8) * N + n0 + tx];
    __syncthreads();
#pragma unroll
    for (int r = 0; r < 4; ++r)
        wt[(size_t)(n0 + ty + r * 8) * K + k0 + tx] = (bf16_t)s[tx][ty + r * 8];
}

// ---------------------------------------------------------------------------

extern "C" void kernel_launch(void* const* d_in, const int* in_sizes, int n_in,
                              void* d_out, int out_size, void* d_ws, size_t ws_size,
                              hipStream_t stream)
{
    const int B = 8, L1 = 2048, L2 = 2048, D1 = 1024, D2 = 768, E = 1024;
    const float scale = 0.03125f;  // E^-0.5
    const int tsh = 11;            // log2(L2)

    const float* m1   = (const float*)d_in[0];
    const float* m2   = (const float*)d_in[1];
    const float* ln1g = (const float*)d_in[2];
    const float* ln1b = (const float*)d_in[3];
    const float* ln2g = (const float*)d_in[4];
    const float* ln2b = (const float*)d_in[5];
    const float* Wq   = (const float*)d_in[6];
    const float* bq   = (const float*)d_in[7];
    const float* Wk   = (const float*)d_in[8];
    const float* bk   = (const float*)d_in[9];
    const float* Wv   = (const float*)d_in[10];
    const float* bv   = (const float*)d_in[11];
    const float* Wo   = (const float*)d_in[12];
    const float* bo   = (const float*)d_in[13];
    float* out = (float*)d_out;

    bf16_t* ws = (bf16_t*)d_ws;
    size_t off = 0;
    auto alloc = [&](size_t n) { bf16_t* p = ws + off; off += n; return p; };
    bf16_t* WqT = alloc((size_t)E * D1);
    bf16_t* WkT = alloc((size_t)E * D2);
    bf16_t* WvT = alloc((size_t)E * D2);
    bf16_t* WoT = alloc((size_t)D1 * E);
    bf16_t* x1  = alloc((size_t)B * L1 * D1);
    bf16_t* x2  = alloc((size_t)B * L2 * D2);
    bf16_t* Qb  = alloc((size_t)B * L1 * E);
    bf16_t* Kb  = alloc((size_t)B * L2 * E);
    bf16_t* VTb = alloc((size_t)B * E * L2);   // V^T, written directly by proj
    bf16_t* ctx = alloc((size_t)B * L1 * E);
    bf16_t* attn = ws + off;
    const bool batched = (off + (size_t)B * L1 * L2) * sizeof(bf16_t) <= ws_size;

    dim3 blk256(256);
    dim3 blk512(512);

    // 1. weights -> bf16 transposed
    wconvT<<<dim3(E / 32, D1 / 32), dim3(32, 8), 0, stream>>>(Wq, WqT, D1, E);
    wconvT<<<dim3(E / 32, D2 / 32), dim3(32, 8), 0, stream>>>(Wk, WkT, D2, E);
    wconvT<<<dim3(E / 32, D2 / 32), dim3(32, 8), 0, stream>>>(Wv, WvT, D2, E);
    wconvT<<<dim3(D1 / 32, E / 32), dim3(32, 8), 0, stream>>>(Wo, WoT, E, D1);

    // 2. layernorms -> bf16
    layernorm_k<4><<<dim3(B * L1 / 4), blk256, 0, stream>>>(m1, ln1g, ln1b, x1);
    layernorm_k<3><<<dim3(B * L2 / 4), blk256, 0, stream>>>(m2, ln2g, ln2b, x2);

    // 3. projections (V writes V^T directly via STORE_T epilogue)
    gemm_bt<bf16_t, true><<<dim3(E / 256, B * L1 / 256, 1), blk512, 0, stream>>>(
        x1, WqT, Qb, bq, B * L1, E, D1, 1.0f, 0, 0, 0, 0);
    gemm_bt<bf16_t, true><<<dim3(E / 256, B * L2 / 256, 1), blk512, 0, stream>>>(
        x2, WkT, Kb, bk, B * L2, E, D2, 1.0f, 0, 0, 0, 0);
    gemm_bt<bf16_t, true, true><<<dim3(E / 256, B * L2 / 256, 1), blk512, 0, stream>>>(
        x2, WvT, VTb, bv, B * L2, E, D2, 1.0f, 0, 0, 0, tsh);

    // 4. attention
    if (batched) {
        gemm_bt<bf16_t, false><<<dim3(L2 / 256, L1 / 256, B), blk512, 0, stream>>>(
            Qb, Kb, attn, nullptr, L1, L2, E, scale,
            (size_t)L1 * E, (size_t)L2 * E, (size_t)L1 * L2, 0);
        softmax_rows<<<dim3(B * L1 / 4), blk256, 0, stream>>>(attn);
        gemm_bt<bf16_t, false><<<dim3(E / 256, L1 / 256, B), blk512, 0, stream>>>(
            attn, VTb, ctx, nullptr, L1, E, L2, 1.0f,
            (size_t)L1 * L2, (size_t)E * L2, (size_t)L1 * E, 0);
    } else {
        for (int b = 0; b < B; ++b) {
            gemm_bt<bf16_t, false><<<dim3(L2 / 256, L1 / 256, 1), blk512, 0, stream>>>(
                Qb + (size_t)b * L1 * E, Kb + (size_t)b * L2 * E, attn, nullptr,
                L1, L2, E, scale, 0, 0, 0, 0);
            softmax_rows<<<dim3(L1 / 4), blk256, 0, stream>>>(attn);
            gemm_bt<bf16_t, false><<<dim3(E / 256, L1 / 256, 1), blk512, 0, stream>>>(
                attn, VTb + (size_t)b * E * L2, ctx + (size_t)b * L1 * E, nullptr,
                L1, E, L2, 1.0f, 0, 0, 0, 0);
        }
    }

    // 5. output projection -> fp32 d_out
    gemm_bt<float, true><<<dim3(D1 / 256, B * L1 / 256, 1), blk512, 0, stream>>>(
        ctx, WoT, out, bo, B * L1, D1, E, 1.0f, 0, 0, 0, 0);
}

// Round 2
// 514.458 us; speedup vs baseline: 1.1141x; 1.1141x over previous
//
#include <hip/hip_runtime.h>
#include <hip/hip_bf16.h>

typedef __bf16 bf16_t;
typedef __bf16 bf16x4_t __attribute__((ext_vector_type(4)));
typedef __bf16 bf16x8_t __attribute__((ext_vector_type(8)));
typedef float f32x4_t __attribute__((ext_vector_type(4)));
typedef float f32x16_t __attribute__((ext_vector_type(16)));

typedef __attribute__((address_space(1))) void gvoid_t;
typedef __attribute__((address_space(3))) void svoid_t;

__device__ __forceinline__ void gload_lds16(const void* g, void* s) {
    // async global->LDS, 16B per lane; LDS dest = wave-uniform base + lane*16
    __builtin_amdgcn_global_load_lds((gvoid_t*)g, (svoid_t*)s, 16, 0, 0);
}

// Raw barrier WITHOUT the implicit vmcnt(0) drain __syncthreads() emits.
__device__ __forceinline__ void wg_barrier() {
    asm volatile("" ::: "memory");
    __builtin_amdgcn_s_barrier();
    asm volatile("" ::: "memory");
}

// ---------------------------------------------------------------------------
// GEMM: C[M,N] = scale * (A[M,K] @ Bt[N,K]^T) + bias
//
// R5: 256x256 tile, 512 threads (8 waves, 2Mx4N), BK=64, 2-buffer LDS
// double-buffer, ONE barrier per K-tile (R1's 2-barrier/BK=32 lockstep was
// the regression: 3900cy/K-step vs 1030cy MFMA floor).
//
// Ledger (provable):
//  - iter t: issue all 8 gload_lds for tile t+1 into buf^1. Previous
//    occupant (tile t-1) was fully consumed before the last barrier
//    (lgkmcnt(0) precedes it) -> no WAR race.
//  - end of iter t: vmcnt(0)+lgkmcnt(0)+barrier -> tile t+1 landed before
//    its first ds_read. Stage latency hides under ~2100cy of tile-t compute.
//
// LDS layout [row][64] bf16 (128B rows), 16B-chunk XOR swizzle:
//   physical_chunk = logical_chunk ^ (row & 7)
// applied to the GLOBAL source on staging (DMA forces linear LDS dest) and
// to the LDS offset on reads. Bank check: each consecutive-8-lane group of a
// ds_read_b128 covers 8 distinct 16B columns = all 32 banks -> conflict-free.
//
// Fragments/epilogue: verified 32x32x16 mappings (unchanged from R3/R4).
// ---------------------------------------------------------------------------
template <typename CT, bool BIAS, bool STORE_T = false>
__global__ __launch_bounds__(512, 2)
void gemm_bt(const bf16_t* __restrict__ A, const bf16_t* __restrict__ Bt,
             CT* __restrict__ C, const float* __restrict__ bias,
             int M, int N, int K, float scale,
             size_t sA, size_t sB, size_t sC, int tshift)
{
    __shared__ bf16_t As[2 * 256 * 64];   // 64 KiB
    __shared__ bf16_t Bs[2 * 256 * 64];   // 64 KiB

    // ---- tile swizzle (XCD remap + bands of 8 by-rows) --------------------
    const int nx = gridDim.x, ny = gridDim.y;
    const int nblk = nx * ny * (int)gridDim.z;
    int lin = blockIdx.x + nx * (blockIdx.y + ny * blockIdx.z);
    int tile = lin;
    if ((nblk & 7) == 0)
        tile = (lin & 7) * (nblk >> 3) + (lin >> 3);
    const int per_z = nx * ny;
    const int bz = tile / per_z;
    int t = tile - bz * per_z;
    const int SB = 8;
    const int band = t / (nx * SB);
    const int r = t - band * (nx * SB);
    const int h = min(SB, ny - band * SB);
    const int bx = r / h;
    const int by = band * SB + (r - bx * h);
    // -----------------------------------------------------------------------

    A  += (size_t)bz * sA;
    Bt += (size_t)bz * sB;
    C  += (size_t)bz * sC;

    const int tid  = threadIdx.x;          // 0..511
    const int wave = tid >> 6;
    const int lane = tid & 63;
    const int m0 = by * 256;
    const int n0 = bx * 256;

    // ---- staging addressing ----------------------------------------------
    // chunk c = j*512 + tid (j=0..3), row = c>>3 (64 bf16 = 8 chunks/row),
    // physical col-chunk = c&7 holds logical chunk (c&7)^(row&7).
    // Per-pass j: row += 64, (row&7) and (c&7) invariant -> one lc per thread.
    const int srow = tid >> 3;                          // 0..63
    const int lc8  = ((tid & 7) ^ (srow & 7)) * 8;      // logical col (elems)
    const bf16_t* Ag = A  + (size_t)(m0 + srow) * K + lc8;
    const bf16_t* Bg = Bt + (size_t)(n0 + srow) * K + lc8;
    const size_t rs = (size_t)64 * K;                   // 64 rows per pass
    const int sbase = wave * 512;                       // elems; +lane*16B auto

    // ---- fragment addressing (32x32x16) -----------------------------------
    //   A/B operand: m(or n) = lane&31, k = (lane>>5)*8 + j
    const int wm = wave >> 2;              // 0..1 -> rows wm*128..+128
    const int wn = wave & 3;               // 0..3 -> cols wn*64..+64
    const int lr = lane & 31;
    const int kh = lane >> 5;
    const int rsw = lr & 7;                // row&7 (mi*32/wm*128 are 0 mod 8)

    f32x16_t acc[4][2];
#pragma unroll
    for (int i = 0; i < 4; ++i)
#pragma unroll
        for (int j = 0; j < 2; ++j)
            acc[i][j] = (f32x16_t)(0.f);

    const int NT = K >> 6;                 // K-tiles of 64

    auto stage = [&](int buf) {
        bf16_t* a = As + buf * 16384;
        bf16_t* b = Bs + buf * 16384;
        const bf16_t* ap = Ag;
        const bf16_t* bp = Bg;
#pragma unroll
        for (int j = 0; j < 4; ++j) {
            gload_lds16(ap, a + j * 4096 + sbase);
            gload_lds16(bp, b + j * 4096 + sbase);
            ap += rs; bp += rs;
        }
        Ag += 64; Bg += 64;                // advance to next K-tile
    };

    stage(0);
    asm volatile("s_waitcnt vmcnt(0)" ::: "memory");
    wg_barrier();

    for (int kt = 0; kt < NT; ++kt) {
        const int buf = kt & 1;
        if (kt + 1 < NT) stage(buf ^ 1);   // all 8 loads issued up front

        const bf16_t* ab = As + buf * 16384;
        const bf16_t* bb = Bs + buf * 16384;

        // 4 code-phases: (kp, mp); B read once per kp, A per phase.
        // 24 ds_read_b128 + 32 MFMA per wave per K-tile, compiler-interleaved.
#pragma unroll
        for (int kp = 0; kp < 2; ++kp) {
            bf16x8_t bfr[2][2];
#pragma unroll
            for (int nj = 0; nj < 2; ++nj)
#pragma unroll
                for (int kq = 0; kq < 2; ++kq)
                    bfr[nj][kq] = *(const bf16x8_t*)
                        &bb[(wn * 64 + nj * 32 + lr) * 64 +
                            (((kp * 2 + kq) * 2 + kh) ^ rsw) * 8];
#pragma unroll
            for (int mp = 0; mp < 2; ++mp) {
                bf16x8_t af[2][2];
#pragma unroll
                for (int mq = 0; mq < 2; ++mq)
#pragma unroll
                    for (int kq = 0; kq < 2; ++kq)
                        af[mq][kq] = *(const bf16x8_t*)
                            &ab[(wm * 128 + (mp * 2 + mq) * 32 + lr) * 64 +
                                (((kp * 2 + kq) * 2 + kh) ^ rsw) * 8];
                __builtin_amdgcn_s_setprio(1);
#pragma unroll
                for (int mq = 0; mq < 2; ++mq)
#pragma unroll
                    for (int nj = 0; nj < 2; ++nj)
#pragma unroll
                        for (int kq = 0; kq < 2; ++kq)
                            acc[mp * 2 + mq][nj] =
                                __builtin_amdgcn_mfma_f32_32x32x16_bf16(
                                    af[mq][kq], bfr[nj][kq],
                                    acc[mp * 2 + mq][nj], 0, 0, 0);
                __builtin_amdgcn_s_setprio(0);
            }
        }

        // next tile landed + my LDS reads retired, then release buffers
        asm volatile("s_waitcnt vmcnt(0) lgkmcnt(0)" ::: "memory");
        wg_barrier();
    }

    // 32x32 C/D layout: col = lane&31, row = (reg&3)+8*(reg>>2)+4*(lane>>5)
#pragma unroll
    for (int nj = 0; nj < 2; ++nj) {
        const int col = n0 + wn * 64 + nj * 32 + lr;
        const float bv = BIAS ? bias[col] : 0.0f;
#pragma unroll
        for (int mi = 0; mi < 4; ++mi) {
            f32x16_t v = acc[mi][nj];
#pragma unroll
            for (int g = 0; g < 4; ++g) {
                const int row = m0 + wm * 128 + mi * 32 + 8 * g + 4 * kh;
                if constexpr (STORE_T) {
                    const int b = row >> tshift;
                    const int l = row & ((1 << tshift) - 1);
                    bf16x4_t o;
#pragma unroll
                    for (int rr2 = 0; rr2 < 4; ++rr2)
                        o[rr2] = (bf16_t)(v[g * 4 + rr2] * scale + bv);
                    *(bf16x4_t*)((bf16_t*)C + ((size_t)b * N << tshift) +
                                 ((size_t)col << tshift) + l) = o;
                } else {
#pragma unroll
                    for (int rr2 = 0; rr2 < 4; ++rr2) {
                        float val = v[g * 4 + rr2] * scale + bv;
                        C[(size_t)(row + rr2) * N + col] = (CT)val;
                    }
                }
            }
        }
    }
}

// ---------------------------------------------------------------------------
// LayerNorm: one wave per row, D = NV*256 (NV float4 per lane). fp32 in,
// bf16 out.
// ---------------------------------------------------------------------------
template <int NV>
__global__ __launch_bounds__(256, 4)
void layernorm_k(const float* __restrict__ x, const float* __restrict__ g,
                 const float* __restrict__ b, bf16_t* __restrict__ y)
{
    const int D = NV * 256;
    const int wave = threadIdx.x >> 6, lane = threadIdx.x & 63;
    const size_t row = (size_t)blockIdx.x * 4 + wave;
    const float4* xr = (const float4*)(x + row * D);

    float4 v[NV];
    float s = 0.f, sq = 0.f;
#pragma unroll
    for (int i = 0; i < NV; ++i) {
        v[i] = xr[lane + 64 * i];
        s  += v[i].x + v[i].y + v[i].z + v[i].w;
        sq += v[i].x * v[i].x + v[i].y * v[i].y + v[i].z * v[i].z + v[i].w * v[i].w;
    }
#pragma unroll
    for (int m = 32; m; m >>= 1) {
        s  += __shfl_xor(s, m, 64);
        sq += __shfl_xor(sq, m, 64);
    }
    const float mean = s / D;
    const float rstd = rsqrtf(fmaxf(sq / D - mean * mean, 0.f) + 1e-5f);

#pragma unroll
    for (int i = 0; i < NV; ++i) {
        const int c4 = lane + 64 * i;
        float4 gg = ((const float4*)g)[c4];
        float4 bb = ((const float4*)b)[c4];
        bf16x4_t o;
        o[0] = (bf16_t)((v[i].x - mean) * rstd * gg.x + bb.x);
        o[1] = (bf16_t)((v[i].y - mean) * rstd * gg.y + bb.y);
        o[2] = (bf16_t)((v[i].z - mean) * rstd * gg.z + bb.z);
        o[3] = (bf16_t)((v[i].w - mean) * rstd * gg.w + bb.w);
        *(bf16x4_t*)(y + row * D + (size_t)c4 * 4) = o;
    }
}

// ---------------------------------------------------------------------------
// In-place row softmax over 2048 bf16 entries; one wave per row.
// ---------------------------------------------------------------------------
__global__ __launch_bounds__(256, 4)
void softmax_rows(bf16_t* __restrict__ a)
{
    const int wave = threadIdx.x >> 6, lane = threadIdx.x & 63;
    const size_t row = (size_t)blockIdx.x * 4 + wave;
    bf16_t* r = a + row * 2048;

    float v[32];
    float mx = -3.0e38f;
#pragma unroll
    for (int i = 0; i < 4; ++i) {
        bf16x8_t t = *(const bf16x8_t*)(r + (size_t)(lane + 64 * i) * 8);
#pragma unroll
        for (int j = 0; j < 8; ++j) {
            v[i * 8 + j] = (float)t[j];
            mx = fmaxf(mx, v[i * 8 + j]);
        }
    }
#pragma unroll
    for (int m = 32; m; m >>= 1) mx = fmaxf(mx, __shfl_xor(mx, m, 64));
    float s = 0.f;
#pragma unroll
    for (int i = 0; i < 32; ++i) { v[i] = __expf(v[i] - mx); s += v[i]; }
#pragma unroll
    for (int m = 32; m; m >>= 1) s += __shfl_xor(s, m, 64);
    const float rs = 1.0f / s;
#pragma unroll
    for (int i = 0; i < 4; ++i) {
        bf16x8_t t;
#pragma unroll
        for (int j = 0; j < 8; ++j) t[j] = (bf16_t)(v[i * 8 + j] * rs);
        *(bf16x8_t*)(r + (size_t)(lane + 64 * i) * 8) = t;
    }
}

// ---------------------------------------------------------------------------
// fp32 weight [K][N] -> bf16 transposed [N][K]. 32x32 LDS tile.
// ---------------------------------------------------------------------------
__global__ __launch_bounds__(256, 4)
void wconvT(const float* __restrict__ w, bf16_t* __restrict__ wt, int K, int N)
{
    __shared__ float s[32][33];
    const int tx = threadIdx.x, ty = threadIdx.y;   // block (32,8)
    const int n0 = blockIdx.x * 32, k0 = blockIdx.y * 32;
#pragma unroll
    for (int r = 0; r < 4; ++r)
        s[ty + r * 8][tx] = w[(size_t)(k0 + ty + r * 8) * N + n0 + tx];
    __syncthreads();
#pragma unroll
    for (int r = 0; r < 4; ++r)
        wt[(size_t)(n0 + ty + r * 8) * K + k0 + tx] = (bf16_t)s[tx][ty + r * 8];
}

// ---------------------------------------------------------------------------

extern "C" void kernel_launch(void* const* d_in, const int* in_sizes, int n_in,
                              void* d_out, int out_size, void* d_ws, size_t ws_size,
                              hipStream_t stream)
{
    const int B = 8, L1 = 2048, L2 = 2048, D1 = 1024, D2 = 768, E = 1024;
    const float scale = 0.03125f;  // E^-0.5
    const int tsh = 11;            // log2(L2)

    const float* m1   = (const float*)d_in[0];
    const float* m2   = (const float*)d_in[1];
    const float* ln1g = (const float*)d_in[2];
    const float* ln1b = (const float*)d_in[3];
    const float* ln2g = (const float*)d_in[4];
    const float* ln2b = (const float*)d_in[5];
    const float* Wq   = (const float*)d_in[6];
    const float* bq   = (const float*)d_in[7];
    const float* Wk   = (const float*)d_in[8];
    const float* bk   = (const float*)d_in[9];
    const float* Wv   = (const float*)d_in[10];
    const float* bv   = (const float*)d_in[11];
    const float* Wo   = (const float*)d_in[12];
    const float* bo   = (const float*)d_in[13];
    float* out = (float*)d_out;

    bf16_t* ws = (bf16_t*)d_ws;
    size_t off = 0;
    auto alloc = [&](size_t n) { bf16_t* p = ws + off; off += n; return p; };
    bf16_t* WqT = alloc((size_t)E * D1);
    bf16_t* WkT = alloc((size_t)E * D2);
    bf16_t* WvT = alloc((size_t)E * D2);
    bf16_t* WoT = alloc((size_t)D1 * E);
    bf16_t* x1  = alloc((size_t)B * L1 * D1);
    bf16_t* x2  = alloc((size_t)B * L2 * D2);
    bf16_t* Qb  = alloc((size_t)B * L1 * E);
    bf16_t* Kb  = alloc((size_t)B * L2 * E);
    bf16_t* VTb = alloc((size_t)B * E * L2);   // V^T, written directly by proj
    bf16_t* ctx = alloc((size_t)B * L1 * E);
    bf16_t* attn = ws + off;
    const bool batched = (off + (size_t)B * L1 * L2) * sizeof(bf16_t) <= ws_size;

    dim3 blk256(256);
    dim3 blk512(512);

    // 1. weights -> bf16 transposed
    wconvT<<<dim3(E / 32, D1 / 32), dim3(32, 8), 0, stream>>>(Wq, WqT, D1, E);
    wconvT<<<dim3(E / 32, D2 / 32), dim3(32, 8), 0, stream>>>(Wk, WkT, D2, E);
    wconvT<<<dim3(E / 32, D2 / 32), dim3(32, 8), 0, stream>>>(Wv, WvT, D2, E);
    wconvT<<<dim3(D1 / 32, E / 32), dim3(32, 8), 0, stream>>>(Wo, WoT, E, D1);

    // 2. layernorms -> bf16
    layernorm_k<4><<<dim3(B * L1 / 4), blk256, 0, stream>>>(m1, ln1g, ln1b, x1);
    layernorm_k<3><<<dim3(B * L2 / 4), blk256, 0, stream>>>(m2, ln2g, ln2b, x2);

    // 3. projections (V writes V^T directly via STORE_T epilogue)
    gemm_bt<bf16_t, true><<<dim3(E / 256, B * L1 / 256, 1), blk512, 0, stream>>>(
        x1, WqT, Qb, bq, B * L1, E, D1, 1.0f, 0, 0, 0, 0);
    gemm_bt<bf16_t, true><<<dim3(E / 256, B * L2 / 256, 1), blk512, 0, stream>>>(
        x2, WkT, Kb, bk, B * L2, E, D2, 1.0f, 0, 0, 0, 0);
    gemm_bt<bf16_t, true, true><<<dim3(E / 256, B * L2 / 256, 1), blk512, 0, stream>>>(
        x2, WvT, VTb, bv, B * L2, E, D2, 1.0f, 0, 0, 0, tsh);

    // 4. attention
    if (batched) {
        gemm_bt<bf16_t, false><<<dim3(L2 / 256, L1 / 256, B), blk512, 0, stream>>>(
            Qb, Kb, attn, nullptr, L1, L2, E, scale,
            (size_t)L1 * E, (size_t)L2 * E, (size_t)L1 * L2, 0);
        softmax_rows<<<dim3(B * L1 / 4), blk256, 0, stream>>>(attn);
        gemm_bt<bf16_t, false><<<dim3(E / 256, L1 / 256, B), blk512, 0, stream>>>(
            attn, VTb, ctx, nullptr, L1, E, L2, 1.0f,
            (size_t)L1 * L2, (size_t)E * L2, (size_t)L1 * E, 0);
    } else {
        for (int b = 0; b < B; ++b) {
            gemm_bt<bf16_t, false><<<dim3(L2 / 256, L1 / 256, 1), blk512, 0, stream>>>(
                Qb + (size_t)b * L1 * E, Kb + (size_t)b * L2 * E, attn, nullptr,
                L1, L2, E, scale, 0, 0, 0, 0);
            softmax_rows<<<dim3(L1 / 4), blk256, 0, stream>>>(attn);
            gemm_bt<bf16_t, false><<<dim3(E / 256, L1 / 256, 1), blk512, 0, stream>>>(
                attn, VTb + (size_t)b * E * L2, ctx + (size_t)b * L1 * E, nullptr,
                L1, E, L2, 1.0f, 0, 0, 0, 0);
        }
    }

    // 5. output projection -> fp32 d_out
    gemm_bt<float, true><<<dim3(D1 / 256, B * L1 / 256, 1), blk512, 0, stream>>>(
        ctx, WoT, out, bo, B * L1, D1, E, 1.0f, 0, 0, 0, 0);
}